// Round 1
// 239.204 us; speedup vs baseline: 1.0112x; 1.0112x over previous
//
#include <hip/hip_runtime.h>
#include <cstddef>

// percnn time stepping: every conv is 1x1 so each output pixel is a pure
// function of the scalars (u,v) at that pixel. Each branch collapses to a
// bivariate cubic in (u,v): 2 x 10 monomial coefficients.
//
// This version FUSES the coefficient computation into the main streaming
// kernel (each block redundantly computes the 20 coefficients from the tiny
// weight vectors, ~2KB, L2-resident). No workspace is touched at all — the
// previous version's d_ws round-trip is gone, along with the second launch.
//
// Monomial order m: 0:u^3 1:u^2v 2:uv^2 3:v^3 4:u^2 5:uv 6:v^2 7:u 8:v 9:1
// out0 = u + sum_m c0[m]*mono_m ; out1 = v + sum_m c1[m]*mono_m
// c0 = DT*(S0 + DU*U-branch), c1 = DT*(S1 + DV*V-branch).

#define HIDC 16

// x: (32, 2, 2, 512, 512) f32; we read t=1 planes. out: (32, 2, 512, 512).
// One thread = one float4 (4 pixels). 8192 blocks x 256 threads covers all
// 2,097,152 groups exactly (HW = 262144 divisible by 4, planes contiguous).
__global__ __launch_bounds__(256) void percnn_fused_kernel(
    const float* __restrict__ x,
    const float* __restrict__ w1u, const float* __restrict__ b1u,
    const float* __restrict__ w2u, const float* __restrict__ b2u,
    const float* __restrict__ w3u, const float* __restrict__ b3u,
    const float* __restrict__ w4u, const float* __restrict__ b4u,
    const float* __restrict__ w1v, const float* __restrict__ b1v,
    const float* __restrict__ w2v, const float* __restrict__ b2v,
    const float* __restrict__ w3v, const float* __restrict__ b3v,
    const float* __restrict__ w4v, const float* __restrict__ b4v,
    const float* __restrict__ w1s, const float* __restrict__ b1s,
    const float* __restrict__ w2s, const float* __restrict__ b2s,
    const float* __restrict__ w3s, const float* __restrict__ b3s,
    const float* __restrict__ w4s, const float* __restrict__ b4s,
    float* __restrict__ out)
{
    // part[c][0..9]  = w4s[0][c] * P_c[m]      (s-branch, output 0)
    // part[c][10..19]= w4s[1][c] * P_c[m]      (s-branch, output 1)
    // part[c][20..23]= w4u[c] * {u3,u2,u,1}    (u diffusion branch)
    // part[c][24..27]= w4v[c] * {v3,v2,v,1}    (v diffusion branch)
    __shared__ float part[HIDC][28];
    __shared__ float red[28];
    __shared__ float cwl[20];

    const int c = threadIdx.x;
    if (c < HIDC) {
        { // u branch: h_i = a_i*u + d_i
            float a1 = w1u[c], d1 = b1u[c];
            float a2 = w2u[c], d2 = b2u[c];
            float a3 = w3u[c], d3 = b3u[c];
            float w4 = w4u[c];
            float X2 = a1 * a2;
            float X1 = a1 * d2 + d1 * a2;
            float X0 = d1 * d2;
            part[c][20] = w4 * (X2 * a3);
            part[c][21] = w4 * (X2 * d3 + X1 * a3);
            part[c][22] = w4 * (X1 * d3 + X0 * a3);
            part[c][23] = w4 * (X0 * d3);
        }
        { // v branch
            float a1 = w1v[c], d1 = b1v[c];
            float a2 = w2v[c], d2 = b2v[c];
            float a3 = w3v[c], d3 = b3v[c];
            float w4 = w4v[c];
            float X2 = a1 * a2;
            float X1 = a1 * d2 + d1 * a2;
            float X0 = d1 * d2;
            part[c][24] = w4 * (X2 * a3);
            part[c][25] = w4 * (X2 * d3 + X1 * a3);
            part[c][26] = w4 * (X1 * d3 + X0 * a3);
            part[c][27] = w4 * (X0 * d3);
        }
        { // s branch: h_i = a_i*u + c_i*v + d_i
            float a1 = w1s[2 * c], c1 = w1s[2 * c + 1], d1 = b1s[c];
            float a2 = w2s[2 * c], c2 = w2s[2 * c + 1], d2 = b2s[c];
            float a3 = w3s[2 * c], c3 = w3s[2 * c + 1], d3 = b3s[c];
            float w40 = w4s[c], w41 = w4s[HIDC + c];
            // h1*h2 expanded
            float X2 = a1 * a2;
            float XY = a1 * c2 + c1 * a2;
            float Y2 = c1 * c2;
            float X1 = a1 * d2 + d1 * a2;
            float Y1 = c1 * d2 + d1 * c2;
            float X0 = d1 * d2;
            float P[10];
            P[0] = X2 * a3;                      // u^3
            P[1] = X2 * c3 + XY * a3;            // u^2 v
            P[2] = XY * c3 + Y2 * a3;            // u v^2
            P[3] = Y2 * c3;                      // v^3
            P[4] = X2 * d3 + X1 * a3;            // u^2
            P[5] = XY * d3 + X1 * c3 + Y1 * a3;  // u v
            P[6] = Y2 * d3 + Y1 * c3;            // v^2
            P[7] = X1 * d3 + X0 * a3;            // u
            P[8] = Y1 * d3 + X0 * c3;            // v
            P[9] = X0 * d3;                      // 1
#pragma unroll
            for (int m = 0; m < 10; ++m) {
                part[c][m] = w40 * P[m];
                part[c][10 + m] = w41 * P[m];
            }
        }
    }
    __syncthreads();
    if (c < 28) {
        float s = 0.f;
#pragma unroll
        for (int i = 0; i < HIDC; ++i) s += part[i][c];
        red[c] = s;
    }
    __syncthreads();
    if (c == 0) {
        const float DT = 0.05f, DUc = 0.001f, DVc = 0.005f;
        float c0[10], c1[10];
#pragma unroll
        for (int m = 0; m < 10; ++m) { c0[m] = red[m]; c1[m] = red[10 + m]; }
        c0[0] += DUc * red[20];
        c0[4] += DUc * red[21];
        c0[7] += DUc * red[22];
        c0[9] += b4s[0] + DUc * (red[23] + b4u[0]);
        c1[3] += DVc * red[24];
        c1[6] += DVc * red[25];
        c1[8] += DVc * red[26];
        c1[9] += b4s[1] + DVc * (red[27] + b4v[0]);
#pragma unroll
        for (int m = 0; m < 10; ++m) { cwl[m] = DT * c0[m]; cwl[10 + m] = DT * c1[m]; }
    }
    __syncthreads();

    // Broadcast coefficients from LDS (same address across all lanes -> free).
    float c0[10], c1[10];
#pragma unroll
    for (int i = 0; i < 10; ++i) { c0[i] = cwl[i]; c1[i] = cwl[10 + i]; }

    const int HW = 512 * 512;          // 262144 pixels per plane
    const unsigned g = blockIdx.x * blockDim.x + threadIdx.x;
    const unsigned b = g >> 16;        // HW/4 = 65536 float4 groups per plane
    const unsigned r4 = g & 65535u;

    const float4 u4 = ((const float4*)(x + (size_t)(4 * b + 2) * HW))[r4];
    const float4 v4 = ((const float4*)(x + (size_t)(4 * b + 3) * HW))[r4];

    float4 o0, o1;
#define EVAL_UV(U, V, O0, O1)                                                  \
    {                                                                          \
        float uu = (U) * (U), vv = (V) * (V), uvp = (U) * (V);                 \
        O0 = (U) + ((c0[0] * (U) + c0[1] * (V)) * uu +                         \
                    (c0[2] * (U) + c0[3] * (V)) * vv +                         \
                    (c0[4] * uu + c0[5] * uvp + c0[6] * vv) +                  \
                    (c0[7] * (U) + c0[8] * (V) + c0[9]));                      \
        O1 = (V) + ((c1[0] * (U) + c1[1] * (V)) * uu +                         \
                    (c1[2] * (U) + c1[3] * (V)) * vv +                         \
                    (c1[4] * uu + c1[5] * uvp + c1[6] * vv) +                  \
                    (c1[7] * (U) + c1[8] * (V) + c1[9]));                      \
    }
    EVAL_UV(u4.x, v4.x, o0.x, o1.x);
    EVAL_UV(u4.y, v4.y, o0.y, o1.y);
    EVAL_UV(u4.z, v4.z, o0.z, o1.z);
    EVAL_UV(u4.w, v4.w, o0.w, o1.w);
#undef EVAL_UV

    ((float4*)(out + (size_t)(2 * b) * HW))[r4] = o0;
    ((float4*)(out + (size_t)(2 * b + 1) * HW))[r4] = o1;
}

extern "C" void kernel_launch(void* const* d_in, const int* in_sizes, int n_in,
                              void* d_out, int out_size, void* d_ws, size_t ws_size,
                              hipStream_t stream) {
    const float* x = (const float*)d_in[0];
    const float* w1u = (const float*)d_in[1];
    const float* b1u = (const float*)d_in[2];
    const float* w2u = (const float*)d_in[3];
    const float* b2u = (const float*)d_in[4];
    const float* w3u = (const float*)d_in[5];
    const float* b3u = (const float*)d_in[6];
    const float* w4u = (const float*)d_in[7];
    const float* b4u = (const float*)d_in[8];
    const float* w1v = (const float*)d_in[9];
    const float* b1v = (const float*)d_in[10];
    const float* w2v = (const float*)d_in[11];
    const float* b2v = (const float*)d_in[12];
    const float* w3v = (const float*)d_in[13];
    const float* b3v = (const float*)d_in[14];
    const float* w4v = (const float*)d_in[15];
    const float* b4v = (const float*)d_in[16];
    const float* w1s = (const float*)d_in[17];
    const float* b1s = (const float*)d_in[18];
    const float* w2s = (const float*)d_in[19];
    const float* b2s = (const float*)d_in[20];
    const float* w3s = (const float*)d_in[21];
    const float* b3s = (const float*)d_in[22];
    const float* w4s = (const float*)d_in[23];
    const float* b4s = (const float*)d_in[24];
    float* out = (float*)d_out;
    (void)d_ws; (void)ws_size;   // workspace deliberately untouched

    // 2,097,152 float4 groups / 256 = 8192 blocks, exact cover
    percnn_fused_kernel<<<8192, 256, 0, stream>>>(
        x,
        w1u, b1u, w2u, b2u, w3u, b3u, w4u, b4u,
        w1v, b1v, w2v, b2v, w3v, b3v, w4v, b4v,
        w1s, b1s, w2s, b2s, w3s, b3s, w4s, b4s,
        out);
}